// Round 13
// baseline (144.562 us; speedup 1.0000x reference)
//
#include <hip/hip_runtime.h>
#include <math.h>

#define HW   4096
#define CIN  64
#define NC1  8
#define NC2  32
#define NB   4
#define MS   8               // m-splits in k_attn

typedef __attribute__((ext_vector_type(8))) short short8;
typedef __attribute__((ext_vector_type(4))) float f32x4;

// ws layout (floats)
#define OFF_DBF    0u        // delta bf16 [4][4096][8]   (ushort)
#define OFF_PBF    65536u    // phi   bf16 [4][4096][8]   (ushort, permuted rows)
#define OFF_GT     131072u   // g^T   bf16 [4][32][4096]  (ushort)
#define OFF_ACC    393216u   // acc f32 [MS][4][4096][32]
#define ACC_STRIDE 524288u   // floats per split (2 MB)
#define OFF_ZPART  4587520u  // [2048]
// total ~18.4 MB

__device__ __forceinline__ ushort f2bf(float f) {
    unsigned u = __float_as_uint(f);
    return (ushort)((u + 0x8000u) >> 16);   // round-half-up to bf16
}

// ---------------- K1: projections -> bf16 delta/phi/g^T ----------------
__global__ __launch_bounds__(256) void k_proj(
    const float* __restrict__ x,
    const float* __restrict__ Wd, const float* __restrict__ bd,
    const float* __restrict__ Wp, const float* __restrict__ bp,
    const float* __restrict__ Wg, const float* __restrict__ bg,
    ushort* __restrict__ dbf, ushort* __restrict__ pbf, ushort* __restrict__ gt)
{
    int gid = blockIdx.x * 256 + threadIdx.x;   // 65536
    int grp = gid >> 14;
    int pf  = gid & 16383;
    int b   = pf >> 12;
    int pos = pf & 4095;

    const float* xb = x + (size_t)b * CIN * HW + pos;

    float a[12];
    if (grp == 0) {
        #pragma unroll
        for (int k = 0; k < 8; ++k) a[k] = bd[k];
        #pragma unroll
        for (int k = 0; k < 4; ++k) a[8 + k] = bp[k];
        #pragma unroll
        for (int c = 0; c < CIN; ++c) {
            float v = xb[(size_t)c * HW];
            #pragma unroll
            for (int k = 0; k < 8; ++k) a[k] = fmaf(v, Wd[k * CIN + c], a[k]);
            #pragma unroll
            for (int k = 0; k < 4; ++k) a[8 + k] = fmaf(v, Wp[k * CIN + c], a[8 + k]);
        }
        short8 dv;
        #pragma unroll
        for (int k = 0; k < 8; ++k) dv[k] = (short)f2bf(a[k]);
        *(short8*)(dbf + (size_t)(b * HW + pos) * NC1) = dv;
        #pragma unroll
        for (int k = 0; k < 4; ++k) {
            int r = k * NB + b; int i = r >> 3; int j = r & 7;
            pbf[((size_t)i * HW + pos) * NC1 + j] = f2bf(a[8 + k]);
        }
    } else if (grp == 1) {
        #pragma unroll
        for (int k = 0; k < 4; ++k) a[k] = bp[4 + k];
        #pragma unroll
        for (int k = 0; k < 8; ++k) a[4 + k] = bg[k];
        #pragma unroll
        for (int c = 0; c < CIN; ++c) {
            float v = xb[(size_t)c * HW];
            #pragma unroll
            for (int k = 0; k < 4; ++k) a[k] = fmaf(v, Wp[(4 + k) * CIN + c], a[k]);
            #pragma unroll
            for (int k = 0; k < 8; ++k) a[4 + k] = fmaf(v, Wg[k * CIN + c], a[4 + k]);
        }
        #pragma unroll
        for (int k = 0; k < 4; ++k) {
            int r = (4 + k) * NB + b; int i = r >> 3; int j = r & 7;
            pbf[((size_t)i * HW + pos) * NC1 + j] = f2bf(a[k]);
        }
        #pragma unroll
        for (int k = 0; k < 8; ++k)
            gt[((size_t)b * NC2 + k) * HW + pos] = f2bf(a[4 + k]);
    } else if (grp == 2) {
        #pragma unroll
        for (int k = 0; k < 12; ++k) a[k] = bg[8 + k];
        #pragma unroll
        for (int c = 0; c < CIN; ++c) {
            float v = xb[(size_t)c * HW];
            #pragma unroll
            for (int k = 0; k < 12; ++k) a[k] = fmaf(v, Wg[(8 + k) * CIN + c], a[k]);
        }
        #pragma unroll
        for (int k = 0; k < 12; ++k)
            gt[((size_t)b * NC2 + 8 + k) * HW + pos] = f2bf(a[k]);
    } else {
        #pragma unroll
        for (int k = 0; k < 12; ++k) a[k] = bg[20 + k];
        #pragma unroll
        for (int c = 0; c < CIN; ++c) {
            float v = xb[(size_t)c * HW];
            #pragma unroll
            for (int k = 0; k < 12; ++k) a[k] = fmaf(v, Wg[(20 + k) * CIN + c], a[k]);
        }
        #pragma unroll
        for (int k = 0; k < 12; ++k)
            gt[((size_t)b * NC2 + 20 + k) * HW + pos] = f2bf(a[k]);
    }
}

// ---------------- K2: MFMA flash, S^T orientation, in-register P exchange ----------------
// grid 2048 = b(4) x nt(64) x ms(8); block 256 = 4 waves x 16 n-rows; no P in LDS.
// S^T = mfma(A=phi, B=delta): lane col=l15=n, regs+group = m. exp in f32.
// cvt_pk pairs -> permlane32_swap + shfl_xor(16) + cndmask redistribute so lane
// group g holds m in [8g,8g+8) -> direct PV A-frag. Verified lane-exact.
__global__ __launch_bounds__(256, 4) void k_attn(
    const ushort* __restrict__ dbf, const ushort* __restrict__ pbf,
    const ushort* __restrict__ gt, float* __restrict__ acc_out,
    float* __restrict__ zpart)
{
    __shared__ float zred[4];

    int bid = blockIdx.x;
    int b   = bid >> 9;
    int rem = bid & 511;
    int nt  = rem >> 3;
    int ms  = rem & 7;
    int tid = threadIdx.x;
    int w   = tid >> 6;
    int l   = tid & 63;
    int l15 = l & 15;
    int g   = l >> 4;
    int n0  = nt * 64 + w * 16;
    int mb0 = ms * 512;
    bool godd = (g & 1) != 0;

    const short8 zero8 = {0, 0, 0, 0, 0, 0, 0, 0};
    const f32x4  zero4 = {0.f, 0.f, 0.f, 0.f};

    // B-frag (delta): col n = l15; k-group 0 (channels 0..7) real, rest zero.
    short8 bdelta = zero8;
    if (g == 0)
        bdelta = *(const short8*)(dbf + (size_t)(b * HW + n0 + l15) * NC1);

    f32x4 acc0 = zero4, acc1 = zero4;
    float z = 0.f;

    const ushort* pb = pbf + (size_t)b * HW * NC1;
    const ushort* gb = gt  + (size_t)b * NC2 * HW;

    for (int mc = 0; mc < 16; ++mc) {
        int mb = mb0 + mc * 32;

        // g^T B-frags: col j = l15 (+16), k-slot (g,i) -> m = mb+8g+i
        short8 bg0 = *(const short8*)(gb + (size_t)l15 * HW + mb + g * 8);
        short8 bg1 = *(const short8*)(gb + (size_t)(l15 + 16) * HW + mb + g * 8);

        // phi A-frags: row m = mb+l15 (+16); k-group 0 real, rest zero
        short8 aphi0 = zero8, aphi1 = zero8;
        if (g == 0) {
            aphi0 = *(const short8*)(pb + (size_t)(mb + l15) * NC1);
            aphi1 = *(const short8*)(pb + (size_t)(mb + 16 + l15) * NC1);
        }

        // S^T: lane holds col n=l15; reg r, group g -> m-local = 4g+r (+16 for s1)
        f32x4 s0 = __builtin_amdgcn_mfma_f32_16x16x32_bf16(aphi0, bdelta, zero4, 0, 0, 0);
        f32x4 s1 = __builtin_amdgcn_mfma_f32_16x16x32_bf16(aphi1, bdelta, zero4, 0, 0, 0);

        float e0 = __expf(s0[0]), e1 = __expf(s0[1]);
        float e2 = __expf(s0[2]), e3 = __expf(s0[3]);
        float e4 = __expf(s1[0]), e5 = __expf(s1[1]);
        float e6 = __expf(s1[2]), e7 = __expf(s1[3]);
        z += ((e0 + e1) + (e2 + e3)) + ((e4 + e5) + (e6 + e7));

        // pack pairs: lo = even m, hi = odd m
        int A0, A1, B0v, B1v;
        asm("v_cvt_pk_bf16_f32 %0, %1, %2" : "=v"(A0)  : "v"(e0), "v"(e1));
        asm("v_cvt_pk_bf16_f32 %0, %1, %2" : "=v"(A1)  : "v"(e2), "v"(e3));
        asm("v_cvt_pk_bf16_f32 %0, %1, %2" : "=v"(B0v) : "v"(e4), "v"(e5));
        asm("v_cvt_pk_bf16_f32 %0, %1, %2" : "=v"(B1v) : "v"(e6), "v"(e7));

        // halves swap: after this A0=P (lo:own-half m0, hi:other reg set), B0v=Q
        asm("v_permlane32_swap_b32 %0, %1" : "+v"(A0), "+v"(B0v));
        asm("v_permlane32_swap_b32 %0, %1" : "+v"(A1), "+v"(B1v));

        int X0  = __shfl_xor(A0, 16);
        int X1  = __shfl_xor(A1, 16);
        int Xq0 = __shfl_xor(B0v, 16);
        int Xq1 = __shfl_xor(B1v, 16);

        union { int u[4]; short8 s8; } pa;
        pa.u[0] = godd ? Xq0 : A0;
        pa.u[1] = godd ? Xq1 : A1;
        pa.u[2] = godd ? B0v : X0;
        pa.u[3] = godd ? B1v : X1;

        acc0 = __builtin_amdgcn_mfma_f32_16x16x32_bf16(pa.s8, bg0, acc0, 0, 0, 0);
        acc1 = __builtin_amdgcn_mfma_f32_16x16x32_bf16(pa.s8, bg1, acc1, 0, 0, 0);
    }

    // store acc (C/D: col j = l15(+16), row n-local = 4g+r)
    float* ao = acc_out + (size_t)ms * ACC_STRIDE + ((size_t)b * HW + n0) * NC2;
    #pragma unroll
    for (int r = 0; r < 4; ++r) {
        int row = 4 * g + r;
        ao[(size_t)row * NC2 + l15]      = acc0[r];
        ao[(size_t)row * NC2 + 16 + l15] = acc1[r];
    }

    #pragma unroll
    for (int off = 32; off > 0; off >>= 1) z += __shfl_xor(z, off);
    if (l == 0) zred[w] = z;
    __syncthreads();
    if (tid == 0) zpart[bid] = zred[0] + zred[1] + zred[2] + zred[3];
}

// ---------------- K3: sum MS acc splits, normalize, conv 32->64, residual ----------------
__global__ __launch_bounds__(256) void k_conv(
    const float* __restrict__ x, const float* __restrict__ Wl,
    const float* __restrict__ bl, const float* __restrict__ acc,
    const float* __restrict__ zpart, float* __restrict__ out)
{
    __shared__ float zl[4];

    int gid = blockIdx.x * 256 + threadIdx.x;   // 65536
    int grp = gid >> 14;                        // wave-uniform
    int pf  = gid & 16383;
    int b   = pf >> 12;                         // block-uniform
    int pos = pf & 4095;
    int tid = threadIdx.x;

    // block-parallel Z reduce (512 partials per b)
    float zv = zpart[b * 512 + tid] + zpart[b * 512 + 256 + tid];
    #pragma unroll
    for (int off = 32; off > 0; off >>= 1) zv += __shfl_xor(zv, off);
    if ((tid & 63) == 0) zl[tid >> 6] = zv;
    __syncthreads();
    float inv = 1.0f / (zl[0] + zl[1] + zl[2] + zl[3]);

    float on_[NC2];
    #pragma unroll
    for (int j = 0; j < NC2; ++j) on_[j] = 0.f;
    #pragma unroll
    for (int s = 0; s < MS; ++s) {
        const float4* ap = (const float4*)(acc + (size_t)s * ACC_STRIDE +
                                           ((size_t)b * HW + pos) * NC2);
        #pragma unroll
        for (int q = 0; q < 8; ++q) {
            float4 v = ap[q];
            on_[q * 4 + 0] += v.x; on_[q * 4 + 1] += v.y;
            on_[q * 4 + 2] += v.z; on_[q * 4 + 3] += v.w;
        }
    }
    #pragma unroll
    for (int j = 0; j < NC2; ++j) on_[j] *= inv;

    const float* xb = x + (size_t)b * CIN * HW + pos;
    float* ob = out + (size_t)b * CIN * HW + pos;
    #pragma unroll
    for (int oo = 0; oo < 16; ++oo) {
        int o = grp * 16 + oo;                  // uniform per wave
        float r = xb[(size_t)o * HW] + bl[o];
        #pragma unroll
        for (int j = 0; j < NC2; ++j) r = fmaf(Wl[o * NC2 + j], on_[j], r);
        ob[(size_t)o * HW] = r;
    }
}

extern "C" void kernel_launch(void* const* d_in, const int* in_sizes, int n_in,
                              void* d_out, int out_size, void* d_ws, size_t ws_size,
                              hipStream_t stream) {
    const float* x  = (const float*)d_in[0];
    const float* Wd = (const float*)d_in[1];
    const float* bd = (const float*)d_in[2];
    const float* Wp = (const float*)d_in[3];
    const float* bp = (const float*)d_in[4];
    const float* Wg = (const float*)d_in[5];
    const float* bg = (const float*)d_in[6];
    const float* Wl = (const float*)d_in[7];
    const float* bl = (const float*)d_in[8];
    float* ws = (float*)d_ws;

    ushort* dbf = (ushort*)(ws + OFF_DBF);
    ushort* pbf = (ushort*)(ws + OFF_PBF);
    ushort* gt  = (ushort*)(ws + OFF_GT);

    k_proj<<<256, 256, 0, stream>>>(x, Wd, bd, Wp, bp, Wg, bg, dbf, pbf, gt);
    k_attn<<<2048, 256, 0, stream>>>(dbf, pbf, gt, ws + OFF_ACC, ws + OFF_ZPART);
    k_conv<<<256, 256, 0, stream>>>(x, Wl, bl, ws + OFF_ACC, ws + OFF_ZPART,
                                    (float*)d_out);
}